// Round 7
// baseline (150.175 us; speedup 1.0000x reference)
//
#include <hip/hip_runtime.h>

// Batched CBF-QP dual FISTA, 4 lanes per problem, packed fp32 (v_pk_fma_f32),
// with wave-uniform convergence early-exit.
// Row partition (25 active rows; all-zero "extra" row provably inert):
//   pair {0,1} owns slack col2: lane0 obs0..5; lane1 obs6..9, slack0, box_a-
//   pair {2,3} owns slack col3: lane2 nei0..5; lane3 nei6, slack1, box_a+, box_w-, box_w+, pad
//   col4 (conn + slack2) replicated in all 4 lanes, packed as one v2 row.
// Early exit: per-iteration primal movement max(|dx0|,|dx1|) accumulated over
// 10-iteration blocks (block-max defeats momentum-oscillation aliasing); a
// wave breaks only when ALL 64 lanes (16 problems) report block movement
// < TOL. Step comes from the same 30 power iterations as the reference, so
// non-exited trajectories match the reference exactly (fp noise only).

typedef float v2f __attribute__((ext_vector_type(2)));

namespace {
constexpr int N_POWER = 30;   // even
constexpr int N_FISTA = 300;  // 30 blocks x 10 iters
constexpr float PINV_S = 1.0f / 200.0f;  // 1/(2*W_SLACK)
constexpr float BIG = 1000.0f;
constexpr float TOL = 2e-4f;  // block-max primal movement; output thresh is 0.35

constexpr double csqrt(double x) {
    double r = x * 0.5 + 0.5;
    for (int i = 0; i < 50; ++i) r = 0.5 * (r + x / r);
    return r;
}
// beta stored pre-duplicated: {b0,b0,b1,b1} per quad -> packed operand needs no splat movs
struct alignas(16) BQuadDup { float b[4]; };
struct BetaTabD { BQuadDup q[N_FISTA / 2]; };
constexpr BetaTabD make_betad() {
    BetaTabD t{};
    float tk = 1.0f;
    for (int k = 0; k < N_FISTA; ++k) {
        const float tk1 = 0.5f * (1.0f + (float)csqrt(1.0 + 4.0 * (double)tk * (double)tk));
        const float bb = (tk - 1.0f) / tk1;
        t.q[k / 2].b[(k % 2) * 2]     = bb;
        t.q[k / 2].b[(k % 2) * 2 + 1] = bb;
        tk = tk1;
    }
    return t;
}
}
__constant__ BetaTabD BETAD = make_betad();

template <int CTRL>
__device__ __forceinline__ float dpp_xor_add(float x) {
    // CTRL: 0xB1 = quad_perm(1,0,3,2) = xor1 ; 0x4E = quad_perm(2,3,0,1) = xor2
    int perm = __builtin_amdgcn_mov_dpp(__float_as_int(x), CTRL, 0xF, 0xF, true);
    return x + __int_as_float(perm);
}

__device__ __forceinline__ v2f vfma(v2f a, v2f b, v2f c) {
    return __builtin_elementwise_fma(a, b, c);
}
__device__ __forceinline__ v2f vmax0(v2f a) {
    const v2f z = {0.f, 0.f};
    return __builtin_elementwise_max(a, z);
}

__global__ __launch_bounds__(256, 2) void cbf_fista10(
    const float* __restrict__ u_nom,    // (B,2)
    const float* __restrict__ v_cur,    // (B,1)
    const float* __restrict__ p_obs,    // (B,10,2)
    const float* __restrict__ obs_mask, // (B,10)
    const float* __restrict__ p_ag,     // (B,7,2)
    const float* __restrict__ v_ag,     // (B,7,2)
    const float* __restrict__ ag_mask,  // (B,7)
    const float* __restrict__ p_c,      // (B,1,2)
    const float* __restrict__ v_c,      // (B,1,2)
    const float* __restrict__ c_mask,   // (B,1)
    float* __restrict__ out,            // (B,2)
    int B)
{
    const int t = blockIdx.x * 256 + threadIdx.x;
    const int p = t >> 2;
    const int sub = t & 3;
    if (p >= B) return;

    const float v  = v_cur[p];
    const float u0 = u_nom[2 * p];
    const float u1 = u_nom[2 * p + 1];

    float r0[6], r1[6], rA[6], nb[6];
#pragma unroll
    for (int s = 0; s < 6; ++s) { r0[s] = 0.f; r1[s] = 0.f; rA[s] = 0.f; nb[s] = -BIG; }

    auto obs_row = [&](int i, int s) {
        const float lx = p_obs[(p * 10 + i) * 2];
        const float ly = p_obs[(p * 10 + i) * 2 + 1];
        const float m  = obs_mask[p * 10 + i];
        const float h   = lx * lx + ly * ly - 0.25f;            // D_OBS^2
        const float hd  = -2.f * lx * v;
        const float rhs = 2.f * v * v + 3.f * hd + 2.f * h;     // DAMP=3, STIFF=2
        r0[s] = 2.f * lx * m;
        r1[s] = 2.f * ly * v * m;
        rA[s] = -m;
        nb[s] = (m > 0.f) ? -rhs : -BIG;
    };
    auto nei_row = [&](int j, int s) {
        const float ax  = p_ag[(p * 7 + j) * 2];
        const float ay  = p_ag[(p * 7 + j) * 2 + 1];
        const float vjx = v_ag[(p * 7 + j) * 2];
        const float vjy = v_ag[(p * 7 + j) * 2 + 1];
        const float m   = ag_mask[p * 7 + j];
        const float h   = ax * ax + ay * ay - 0.64f;            // D_SAFE^2
        const float hd  = -2.f * ax * v + 2.f * (ax * vjx + ay * vjy);
        const float hdd = 2.f * v * v - 2.f * v * vjx
                        + 2.f * (-v * vjx + vjx * vjx + vjy * vjy);
        const float rhs = hdd + 3.f * hd + 2.f * h;             // DAMP_A=3, STIFF_A=2
        r0[s] = 2.f * ax * m;
        r1[s] = (2.f * ay * v - 2.f * ay * vjx + 2.f * ax * vjy) * m;
        rA[s] = -m;
        nb[s] = (m > 0.f) ? -rhs : -BIG;
    };

    if (sub == 0) {
        obs_row(0, 0); obs_row(1, 1); obs_row(2, 2);
        obs_row(3, 3); obs_row(4, 4); obs_row(5, 5);
    } else if (sub == 1) {
        obs_row(6, 0); obs_row(7, 1); obs_row(8, 2); obs_row(9, 3);
        rA[4] = -1.f; nb[4] = 0.f;     // slack0: -delta_obs <= 0 (col2)
        r0[5] = -1.f; nb[5] = -2.f;    // -a <= A_MAX
    } else if (sub == 2) {
        nei_row(0, 0); nei_row(1, 1); nei_row(2, 2);
        nei_row(3, 3); nei_row(4, 4); nei_row(5, 5);
    } else {
        nei_row(6, 0);
        rA[1] = -1.f; nb[1] = 0.f;     // slack1: -delta_agent <= 0 (col3)
        r0[2] =  1.f; nb[2] = -2.f;    //  a <= A_MAX
        r1[3] = -1.f; nb[3] = -1.f;    // -w <= W_MAX
        r1[4] =  1.f; nb[4] = -1.f;    //  w <= W_MAX
        // slot5 = pad (zero coeffs, nb=-BIG): lambda provably stays 0
    }

    // pack 6 scalar slots into 3 packed slots
    v2f R0[3], R1[3], RA[3], NB[3];
#pragma unroll
    for (int k = 0; k < 3; ++k) {
        R0[k] = v2f{r0[2 * k], r0[2 * k + 1]};
        R1[k] = v2f{r1[2 * k], r1[2 * k + 1]};
        RA[k] = v2f{rA[2 * k], rA[2 * k + 1]};
        NB[k] = v2f{nb[2 * k], nb[2 * k + 1]};
    }

    // conn + slack2 (col4), replicated in every lane, packed as one v2 row
    float c0, c1, cB;
    v2f C0v, C1v, CB2, NCBv;
    {
        const float cx  = p_c[2 * p];
        const float cy  = p_c[2 * p + 1];
        const float cvx = v_c[2 * p];
        const float cvy = v_c[2 * p + 1];
        const float m   = c_mask[p];
        const float h   = 25.f - (cx * cx + cy * cy);           // D_MAX^2
        const float hd  = 2.f * cx * v - 2.f * (cx * cvx + cy * cvy);
        const float hdd = -(2.f * v * v - 2.f * v * cvx
                          + 2.f * (-v * cvx + cvx * cvx + cvy * cvy));
        const float rhs = hdd + 3.f * hd + 2.f * h;             // DAMP_CN=3, STIFF_CN=2
        c0 = -2.f * cx * m;
        c1 = -(2.f * cy * v - 2.f * cy * cvx + 2.f * cx * cvy) * m;
        cB = -m;
        const float ncb = (m > 0.f) ? -rhs : -BIG;
        C0v  = v2f{c0, 0.f};
        C1v  = v2f{c1, 0.f};
        CB2  = v2f{cB, -1.f};
        NCBv = v2f{ncb, 0.f};
    }

    // ---- Power iteration: L = lambda_max(A Pinv A^T), normalize every 2nd ----
    v2f PV[3];
#pragma unroll
    for (int k = 0; k < 3; ++k) PV[k] = v2f{1.f, 1.f};
    float pvC = 1.f, pvS = 1.f;

    auto apply_M = [&]() {
        v2f A0 = vfma(R0[0], PV[0], vfma(R0[1], PV[1], R0[2] * PV[2]));
        v2f A1 = vfma(R1[0], PV[0], vfma(R1[1], PV[1], R1[2] * PV[2]));
        v2f AA = vfma(RA[0], PV[0], vfma(RA[1], PV[1], RA[2] * PV[2]));
        float a0 = A0.x + A0.y, a1 = A1.x + A1.y, aA = AA.x + AA.y;
        a0 = dpp_xor_add<0xB1>(a0); a0 = dpp_xor_add<0x4E>(a0);
        a1 = dpp_xor_add<0xB1>(a1); a1 = dpp_xor_add<0x4E>(a1);
        aA = dpp_xor_add<0xB1>(aA);
        a0 = fmaf(c0, pvC, a0);
        a1 = fmaf(c1, pvC, a1);
        const float aC = fmaf(cB, pvC, -pvS);
        const float x0 = 0.5f * a0, x1 = 0.5f * a1;
        const float xA = PINV_S * aA, xC = PINV_S * aC;
        const v2f X0 = {x0, x0}, X1 = {x1, x1}, XA = {xA, xA};
#pragma unroll
        for (int k = 0; k < 3; ++k)
            PV[k] = vfma(R0[k], X0, vfma(R1[k], X1, RA[k] * XA));
        pvC = fmaf(c0, x0, fmaf(c1, x1, cB * xC));
        pvS = -xC;
    };

#pragma unroll 1
    for (int o = 0; o < N_POWER / 2; ++o) {
        apply_M();
        apply_M();
        v2f NS = vfma(PV[0], PV[0], vfma(PV[1], PV[1], PV[2] * PV[2]));
        float nsq = NS.x + NS.y;
        nsq = dpp_xor_add<0xB1>(nsq); nsq = dpp_xor_add<0x4E>(nsq);
        nsq = fmaf(pvC, pvC, fmaf(pvS, pvS, nsq));
        const float inv = __builtin_amdgcn_rsqf(nsq + 1e-24f);
        const v2f INV = {inv, inv};
#pragma unroll
        for (int k = 0; k < 3; ++k) PV[k] = PV[k] * INV;
        pvC *= inv;
        pvS *= inv;
    }
    float nsh, pA;   // -step/2, -step*PINV_S
    {
        v2f A0 = vfma(R0[0], PV[0], vfma(R0[1], PV[1], R0[2] * PV[2]));
        v2f A1 = vfma(R1[0], PV[0], vfma(R1[1], PV[1], R1[2] * PV[2]));
        v2f AA = vfma(RA[0], PV[0], vfma(RA[1], PV[1], RA[2] * PV[2]));
        float a0 = A0.x + A0.y, a1 = A1.x + A1.y, aA = AA.x + AA.y;
        a0 = dpp_xor_add<0xB1>(a0); a0 = dpp_xor_add<0x4E>(a0);
        a1 = dpp_xor_add<0xB1>(a1); a1 = dpp_xor_add<0x4E>(a1);
        aA = dpp_xor_add<0xB1>(aA);
        a0 = fmaf(c0, pvC, a0);
        a1 = fmaf(c1, pvC, a1);
        const float aC = fmaf(cB, pvC, -pvS);
        // pair sums of slack cols: after xor1, lanes {0,1} hold col2, {2,3} col3
        float tq = aA * aA;
        tq = dpp_xor_add<0x4E>(tq);     // col2^2 + col3^2 in every lane
        const float L = 0.5f * (a0 * a0 + a1 * a1) + PINV_S * (tq + aC * aC);
        const float step = __builtin_amdgcn_rcpf(L + 1e-6f);
        nsh = -0.5f * step;
        pA  = -PINV_S * step;
    }

    // ---- FISTA on the dual, z = y/step scale, packed, lambda ping-pong ----
    v2f LAE[3], LAO[3], ZV[3];
#pragma unroll
    for (int k = 0; k < 3; ++k) {
        LAE[k] = v2f{0.f, 0.f}; LAO[k] = v2f{0.f, 0.f}; ZV[k] = v2f{0.f, 0.f};
    }
    v2f laCSE = {0.f, 0.f}, laCSO = {0.f, 0.f}, zCS = {0.f, 0.f};  // {conn, slack2}
    float x0p = u0, x1p = u1, dmax = 0.f;   // primal-movement tracking

    auto half_step = [&](v2f (&ln_)[3], const v2f (&lp_)[3],
                         v2f& lnCS, v2f lpCS, v2f Bv) {
        v2f A0 = vfma(R0[0], ZV[0], vfma(R0[1], ZV[1], R0[2] * ZV[2]));
        v2f A1 = vfma(R1[0], ZV[0], vfma(R1[1], ZV[1], R1[2] * ZV[2]));
        v2f AA = vfma(RA[0], ZV[0], vfma(RA[1], ZV[1], RA[2] * ZV[2]));
        float a0 = A0.x + A0.y, a1 = A1.x + A1.y, aA = AA.x + AA.y;
        a0 = dpp_xor_add<0xB1>(a0); a0 = dpp_xor_add<0x4E>(a0);
        a1 = dpp_xor_add<0xB1>(a1); a1 = dpp_xor_add<0x4E>(a1);
        aA = dpp_xor_add<0xB1>(aA);
        const v2f tC = CB2 * zCS;           // {cB*zC, -zS}
        const float sCz = tC.x + tC.y;
        const float x0 = fmaf(nsh, fmaf(c0, zCS.x, a0), u0);  // x = -(q + A^T y)*Pinv
        const float x1 = fmaf(nsh, fmaf(c1, zCS.x, a1), u1);
        const float xA = pA * aA;
        const float xC = pA * sCz;
        // convergence tracking: block-max primal movement
        dmax = fmaxf(dmax, fmaxf(fabsf(x0 - x0p), fabsf(x1 - x1p)));
        x0p = x0; x1p = x1;
        const v2f X0 = {x0, x0}, X1 = {x1, x1}, XA = {xA, xA}, XC = {xC, xC};
#pragma unroll
        for (int k = 0; k < 3; ++k) {
            const v2f resid = vfma(R0[k], X0, vfma(R1[k], X1, vfma(RA[k], XA, NB[k])));
            const v2f l = vmax0(ZV[k] + resid);
            ZV[k] = vfma(Bv, l - lp_[k], l);
            ln_[k] = l;
        }
        {   // packed conn(.x) + slack2(.y)
            const v2f resid = vfma(C0v, X0, vfma(C1v, X1, vfma(CB2, XC, NCBv)));
            const v2f l = vmax0(zCS + resid);
            zCS = vfma(Bv, l - lpCS, l);
            lnCS = l;
        }
    };

    // 30 blocks x 10 iterations; wave-uniform early exit when every lane's
    // block-max primal movement is below TOL (16 problems/wave all converged).
#pragma unroll 1
    for (int blk = 0; blk < N_FISTA / 10; ++blk) {
        dmax = 0.f;
#pragma unroll
        for (int u = 0; u < 5; ++u) {
            const BQuadDup bq = BETAD.q[blk * 5 + u];
            const v2f B0 = {bq.b[0], bq.b[1]};
            const v2f B1 = {bq.b[2], bq.b[3]};
            half_step(LAE, LAO, laCSE, laCSO, B0);  // even iter, writes E
            half_step(LAO, LAE, laCSO, laCSE, B1);  // odd iter, writes O
        }
        if (__all(dmax < TOL)) break;   // all 16 problems in the wave converged
    }

    // ---- Final primal from lambda = step*Lambda (last write was LAO / laCSO) ----
    v2f A0 = vfma(R0[0], LAO[0], vfma(R0[1], LAO[1], R0[2] * LAO[2]));
    v2f A1 = vfma(R1[0], LAO[0], vfma(R1[1], LAO[1], R1[2] * LAO[2]));
    float a0 = A0.x + A0.y, a1 = A1.x + A1.y;
    a0 = dpp_xor_add<0xB1>(a0); a0 = dpp_xor_add<0x4E>(a0);
    a1 = dpp_xor_add<0xB1>(a1); a1 = dpp_xor_add<0x4E>(a1);
    a0 = fmaf(c0, laCSO.x, a0);
    a1 = fmaf(c1, laCSO.x, a1);
    if (sub == 0) {
        out[2 * p]     = fmaf(nsh, a0, u0);
        out[2 * p + 1] = fmaf(nsh, a1, u1);
    }
}

extern "C" void kernel_launch(void* const* d_in, const int* in_sizes, int n_in,
                              void* d_out, int out_size, void* d_ws, size_t ws_size,
                              hipStream_t stream) {
    const float* u_nom    = (const float*)d_in[0];
    const float* v_cur    = (const float*)d_in[1];
    const float* p_obs    = (const float*)d_in[2];
    const float* obs_mask = (const float*)d_in[3];
    const float* p_ag     = (const float*)d_in[4];
    const float* v_ag     = (const float*)d_in[5];
    const float* ag_mask  = (const float*)d_in[6];
    const float* p_c      = (const float*)d_in[7];
    const float* v_c      = (const float*)d_in[8];
    const float* c_mask   = (const float*)d_in[9];
    float* out = (float*)d_out;

    const int B = in_sizes[0] / 2;
    const long long threads = 4LL * B;
    const int grid = (int)((threads + 255) / 256);
    cbf_fista10<<<grid, 256, 0, stream>>>(
        u_nom, v_cur, p_obs, obs_mask, p_ag, v_ag, ag_mask, p_c, v_c, c_mask, out, B);
}